// Round 8
// baseline (141.710 us; speedup 1.0000x reference)
//
#include <hip/hip_runtime.h>
#include <hip/hip_bf16.h>
#include <cstdint>

#define N_NODES 50000
#define N_EDGES 640000
#define IN_DIM 128
#define HID_DIM 128
#define OUT_DIM 64

constexpr int EDGE_BLOCKS  = (N_EDGES + 255) / 256;                    // 2500
constexpr int SCAN_BLOCKS  = (N_NODES + 255) / 256;                    // 196
constexpr int WSPLIT_ELEMS = 128 * (HID_DIM + OUT_DIM);                // 24576

typedef __attribute__((ext_vector_type(8))) short bf16x8;
typedef __attribute__((ext_vector_type(4))) float f32x4;

static __device__ __forceinline__ ushort f32_bf16_rn(float f) {
    uint32_t u = __float_as_uint(f);
    u += 0x7fffu + ((u >> 16) & 1u);
    return (ushort)(u >> 16);
}
static __device__ __forceinline__ float bf16_f32(ushort h) {
    return __uint_as_float(((uint32_t)h) << 16);
}

static __device__ __forceinline__ int detect_i64(const void* p) {
    // int64 edge_index (values < 2^31) => every odd int32 word is a zero high-word.
    const int* q = (const int*)p;
    int odd_or = 0, even_or = 0;
#pragma unroll
    for (int i = 1; i < 64; i += 2) odd_or |= q[i];
#pragma unroll
    for (int i = 0; i < 64; i += 2) even_or |= q[i];
    return (odd_or == 0 && even_or != 0) ? 1 : 0;
}

// Prep: zero degcnt AND split/pack both weight matrices (hi/lo bf16, frag order).
// frag = (nt*4 + ks)*64 + g*16 + (j&15), elem e; k = ks*32 + g*8 + e, j = nt*16 + (j&15)
__global__ void k_prep(unsigned int* __restrict__ degcnt,
                       const float* __restrict__ W1, ushort* __restrict__ w1hi,
                       ushort* __restrict__ w1lo, const float* __restrict__ W2,
                       ushort* __restrict__ w2hi, ushort* __restrict__ w2lo) {
    int t = blockIdx.x * blockDim.x + threadIdx.x;
    if (t < N_NODES) degcnt[t] = 0u;
    if (t >= WSPLIT_ELEMS) return;
    const float* W;
    ushort *whi, *wlo;
    int dout, tt = t;
    if (tt < 128 * HID_DIM) {
        W = W1; whi = w1hi; wlo = w1lo; dout = HID_DIM;
    } else {
        tt -= 128 * HID_DIM;
        W = W2; whi = w2hi; wlo = w2lo; dout = OUT_DIM;
    }
    int k = tt / dout, j = tt % dout;
    float w = W[tt];
    ushort hi = f32_bf16_rn(w);
    ushort lo = f32_bf16_rn(w - bf16_f32(hi));
    int nt = j >> 4, ks = k >> 5, g = (k >> 3) & 3, e = k & 7;
    int frag = (nt * 4 + ks) * 64 + g * 16 + (j & 15);
    whi[frag * 8 + e] = hi;
    wlo[frag * 8 + e] = lo;
}

// Single 32-bit atomic per edge (32-bit atomics measured ~8.6/cyc vs ~6.7/cyc
// for 64-bit-with-return — round 4 vs round 7):
//   degcnt[c] += (1<<25) + round(w * 2^19)
// bits [25:31] = edge count (max in-degree ~40 << 127), bits [0:24] = weighted
// degree in 2^-19 fixed point (sum < 64 -> no carry into count field).
// Returned high bits = this edge's rank within its destination segment.
__global__ void k_edges_rank(const void* __restrict__ ei, const float* __restrict__ w,
                             int* __restrict__ rows, int* __restrict__ cols,
                             int* __restrict__ rank,
                             unsigned int* __restrict__ degcnt, int n_edges) {
    __shared__ int is64_s;
    if (threadIdx.x == 0) is64_s = detect_i64(ei);
    __syncthreads();
    int e = blockIdx.x * blockDim.x + threadIdx.x;
    if (e >= n_edges) return;
    int r, c;
    if (is64_s) {
        const long long* q = (const long long*)ei;
        r = (int)q[e];
        c = (int)q[e + n_edges];
    } else {
        const int* q = (const int*)ei;
        r = q[e];
        c = q[e + n_edges];
    }
    rows[e] = r;
    cols[e] = c;
    unsigned int wq = (unsigned int)rintf(w[e] * 524288.0f);  // w * 2^19
    unsigned int old = atomicAdd(&degcnt[c], (1u << 25) + wq);
    rank[e] = (int)(old >> 25);
}

// GEMM1: C_bf16[n,128] = A_f32[n,128] @ W1 via split-bf16 (3 MFMA products).
// 4 waves/block; each wave owns 32 rows (2 m-tiles).
__global__ __launch_bounds__(256) void k_gemm1(const float* __restrict__ A,
                                               const ushort* __restrict__ whi_u,
                                               const ushort* __restrict__ wlo_u,
                                               ushort* __restrict__ C, int n) {
    constexpr int NT = HID_DIM / 16;  // 8
    const bf16x8* whi = (const bf16x8*)whi_u;
    const bf16x8* wlo = (const bf16x8*)wlo_u;
    int wave = threadIdx.x >> 6, lane = threadIdx.x & 63;
    int g = lane >> 4, rr = lane & 15;
    int row_base = blockIdx.x * 128 + wave * 32;

    f32x4 acc[2][NT];
#pragma unroll
    for (int mt = 0; mt < 2; ++mt)
#pragma unroll
        for (int nt = 0; nt < NT; ++nt) acc[mt][nt] = (f32x4){0.f, 0.f, 0.f, 0.f};

#pragma unroll
    for (int ks = 0; ks < 4; ++ks) {
        bf16x8 ahi[2], alo[2];
#pragma unroll
        for (int mt = 0; mt < 2; ++mt) {
            int row = row_base + mt * 16 + rr;
            float av[8];
            if (row < n) {
                const float* ap = &A[(size_t)row * IN_DIM + ks * 32 + g * 8];
                float4 p0 = *(const float4*)ap;
                float4 p1 = *(const float4*)(ap + 4);
                av[0] = p0.x; av[1] = p0.y; av[2] = p0.z; av[3] = p0.w;
                av[4] = p1.x; av[5] = p1.y; av[6] = p1.z; av[7] = p1.w;
            } else {
#pragma unroll
                for (int e = 0; e < 8; ++e) av[e] = 0.f;
            }
            union { bf16x8 v; ushort u[8]; } H, L;
#pragma unroll
            for (int e = 0; e < 8; ++e) {
                ushort h = f32_bf16_rn(av[e]);
                H.u[e] = h;
                L.u[e] = f32_bf16_rn(av[e] - bf16_f32(h));
            }
            ahi[mt] = H.v;
            alo[mt] = L.v;
        }
#pragma unroll
        for (int nt = 0; nt < NT; ++nt) {
            bf16x8 wh = whi[(nt * 4 + ks) * 64 + lane];
            bf16x8 wl = wlo[(nt * 4 + ks) * 64 + lane];
#pragma unroll
            for (int mt = 0; mt < 2; ++mt) {
                acc[mt][nt] = __builtin_amdgcn_mfma_f32_16x16x32_bf16(ahi[mt], wh, acc[mt][nt], 0, 0, 0);
                acc[mt][nt] = __builtin_amdgcn_mfma_f32_16x16x32_bf16(alo[mt], wh, acc[mt][nt], 0, 0, 0);
                acc[mt][nt] = __builtin_amdgcn_mfma_f32_16x16x32_bf16(ahi[mt], wl, acc[mt][nt], 0, 0, 0);
            }
        }
    }
    // C/D layout (m89-verified): col = lane&15, row = (lane>>4)*4 + reg
#pragma unroll
    for (int mt = 0; mt < 2; ++mt) {
#pragma unroll
        for (int r = 0; r < 4; ++r) {
            int row = row_base + mt * 16 + g * 4 + r;
            if (row < n) {
#pragma unroll
                for (int nt = 0; nt < NT; ++nt)
                    C[(size_t)row * HID_DIM + nt * 16 + rr] = f32_bf16_rn(acc[mt][nt][r]);
            }
        }
    }
}

// Block-level exclusive scan over counts (high 7 bits of degcnt); also dinv.
__global__ void k_scan_block(const unsigned int* __restrict__ degcnt,
                             int* __restrict__ starts, int* __restrict__ bsums,
                             float* __restrict__ dinv, int n) {
    __shared__ int buf[256];
    int i = blockIdx.x * 256 + threadIdx.x;
    int v = 0;
    if (i < n) {
        unsigned int dc = degcnt[i];
        v = (int)(dc >> 25);
        float deg = 1.0f + (float)(dc & 0x1ffffffu) * (1.0f / 524288.0f);
        dinv[i] = rsqrtf(deg);  // deg >= 1 always (self-loop)
    }
    buf[threadIdx.x] = v;
    __syncthreads();
#pragma unroll
    for (int off = 1; off < 256; off <<= 1) {
        int t = (threadIdx.x >= off) ? buf[threadIdx.x - off] : 0;
        __syncthreads();
        buf[threadIdx.x] += t;
        __syncthreads();
    }
    if (i < n) starts[i] = buf[threadIdx.x] - v;
    if (threadIdx.x == 255) bsums[blockIdx.x] = buf[255];
}

__global__ void k_scan_tops(int* __restrict__ bsums, int nb) {
    __shared__ int buf[256];
    int v = (threadIdx.x < nb) ? bsums[threadIdx.x] : 0;
    buf[threadIdx.x] = v;
    __syncthreads();
#pragma unroll
    for (int off = 1; off < 256; off <<= 1) {
        int t = (threadIdx.x >= off) ? buf[threadIdx.x - off] : 0;
        __syncthreads();
        buf[threadIdx.x] += t;
        __syncthreads();
    }
    if (threadIdx.x < nb) bsums[threadIdx.x] = buf[threadIdx.x] - v;
}

__global__ void k_scan_add(int* __restrict__ starts, const int* __restrict__ bsums,
                           int n, int total) {
    int i = blockIdx.x * 256 + threadIdx.x;
    if (i < n) starts[i] += bsums[blockIdx.x];
    if (i == 0) starts[n] = total;
}

// Atomic-free CSR fill: pos = starts[c] + rank[e]; packed = {row, norm}.
__global__ void k_fill(const int* __restrict__ rows, const int* __restrict__ cols,
                       const int* __restrict__ rank, const float* __restrict__ w,
                       const float* __restrict__ dinv, const int* __restrict__ starts,
                       int2* __restrict__ packed, int n_edges) {
    int e = blockIdx.x * blockDim.x + threadIdx.x;
    if (e >= n_edges) return;
    int r = rows[e], c = cols[e];
    float nm = dinv[r] * w[e] * dinv[c];
    int pos = starts[c] + rank[e];
    packed[pos] = make_int2(r, __float_as_int(nm));
}

// Gather over bf16 feature rows: TWO nodes per wave (half-wave each) for 2x
// memory-level parallelism; unroll-8 -> 16 independent row fetches in flight.
// D=128: lane covers 4 cols (uint2), ReLU'd bf16 output (h1).
// D=64:  lane covers 2 cols (uint), f32 output (final, float2 stores).
template <int D>
__global__ void k_gather_b(const ushort* __restrict__ htmp, const int2* __restrict__ packed,
                           const int* __restrict__ starts, const float* __restrict__ dinv,
                           const float* __restrict__ bias, void* __restrict__ outv, int n) {
    int wid = (int)((blockIdx.x * (size_t)blockDim.x + threadIdx.x) >> 6);
    int lane = threadIdx.x & 63;
    int half = lane >> 5, hl = lane & 31;
    int node = wid * 2 + half;
    if (node >= n) return;
    int beg = starts[node], end = starts[node + 1];  // uniform within half-wave
    float di = dinv[node];
    float s = di * di;

    if constexpr (D == 128) {
        uint2 us = ((const uint2*)(htmp + (size_t)node * 128))[hl];
        float a0 = bf16_f32((ushort)us.x) * s + bias[4 * hl + 0];
        float a1 = bf16_f32((ushort)(us.x >> 16)) * s + bias[4 * hl + 1];
        float a2 = bf16_f32((ushort)us.y) * s + bias[4 * hl + 2];
        float a3 = bf16_f32((ushort)(us.y >> 16)) * s + bias[4 * hl + 3];
        for (int p0 = beg; p0 < end; p0 += 8) {
            int2 e[8];
#pragma unroll
            for (int u = 0; u < 8; ++u) {
                int p = p0 + u;
                e[u] = packed[p < end ? p : end - 1];
            }
            uint2 v[8];
#pragma unroll
            for (int u = 0; u < 8; ++u)
                v[u] = ((const uint2*)(htmp + (size_t)e[u].x * 128))[hl];
#pragma unroll
            for (int u = 0; u < 8; ++u) {
                float nm = (p0 + u < end) ? __int_as_float(e[u].y) : 0.f;
                a0 = fmaf(bf16_f32((ushort)v[u].x), nm, a0);
                a1 = fmaf(bf16_f32((ushort)(v[u].x >> 16)), nm, a1);
                a2 = fmaf(bf16_f32((ushort)v[u].y), nm, a2);
                a3 = fmaf(bf16_f32((ushort)(v[u].y >> 16)), nm, a3);
            }
        }
        // ReLU + pack bf16 (h1 feeds layer-2 GEMM directly as exact bf16)
        uint o0 = (uint)f32_bf16_rn(fmaxf(a0, 0.f)) | ((uint)f32_bf16_rn(fmaxf(a1, 0.f)) << 16);
        uint o1 = (uint)f32_bf16_rn(fmaxf(a2, 0.f)) | ((uint)f32_bf16_rn(fmaxf(a3, 0.f)) << 16);
        ((uint2*)((ushort*)outv + (size_t)node * 128))[hl] = make_uint2(o0, o1);
    } else {
        uint us = ((const uint*)(htmp + (size_t)node * 64))[hl];
        float a0 = bf16_f32((ushort)us) * s + bias[2 * hl + 0];
        float a1 = bf16_f32((ushort)(us >> 16)) * s + bias[2 * hl + 1];
        for (int p0 = beg; p0 < end; p0 += 8) {
            int2 e[8];
#pragma unroll
            for (int u = 0; u < 8; ++u) {
                int p = p0 + u;
                e[u] = packed[p < end ? p : end - 1];
            }
            uint v[8];
#pragma unroll
            for (int u = 0; u < 8; ++u)
                v[u] = ((const uint*)(htmp + (size_t)e[u].x * 64))[hl];
#pragma unroll
            for (int u = 0; u < 8; ++u) {
                float nm = (p0 + u < end) ? __int_as_float(e[u].y) : 0.f;
                a0 = fmaf(bf16_f32((ushort)v[u]), nm, a0);
                a1 = fmaf(bf16_f32((ushort)(v[u] >> 16)), nm, a1);
            }
        }
        ((float2*)((float*)outv + (size_t)node * 64))[hl] = make_float2(a0, a1);
    }
}

// GEMM2: C_bf16[n,64] = A_bf16[n,128] @ W2, A exact bf16 -> 2 MFMA products.
__global__ __launch_bounds__(128) void k_gemm2(const ushort* __restrict__ A,
                                               const ushort* __restrict__ whi_u,
                                               const ushort* __restrict__ wlo_u,
                                               ushort* __restrict__ C, int n) {
    constexpr int NT = OUT_DIM / 16;  // 4
    const bf16x8* whi = (const bf16x8*)whi_u;
    const bf16x8* wlo = (const bf16x8*)wlo_u;
    int wave = threadIdx.x >> 6, lane = threadIdx.x & 63;
    int g = lane >> 4, rr = lane & 15;
    int row_base = blockIdx.x * 64 + wave * 32;

    f32x4 acc[2][NT];
#pragma unroll
    for (int mt = 0; mt < 2; ++mt)
#pragma unroll
        for (int nt = 0; nt < NT; ++nt) acc[mt][nt] = (f32x4){0.f, 0.f, 0.f, 0.f};

#pragma unroll
    for (int ks = 0; ks < 4; ++ks) {
        bf16x8 a[2];
#pragma unroll
        for (int mt = 0; mt < 2; ++mt) {
            int row = row_base + mt * 16 + rr;
            if (row < n)
                a[mt] = *(const bf16x8*)&A[(size_t)row * HID_DIM + ks * 32 + g * 8];
            else
                a[mt] = (bf16x8){0, 0, 0, 0, 0, 0, 0, 0};
        }
#pragma unroll
        for (int nt = 0; nt < NT; ++nt) {
            bf16x8 wh = whi[(nt * 4 + ks) * 64 + lane];
            bf16x8 wl = wlo[(nt * 4 + ks) * 64 + lane];
#pragma unroll
            for (int mt = 0; mt < 2; ++mt) {
                acc[mt][nt] = __builtin_amdgcn_mfma_f32_16x16x32_bf16(a[mt], wh, acc[mt][nt], 0, 0, 0);
                acc[mt][nt] = __builtin_amdgcn_mfma_f32_16x16x32_bf16(a[mt], wl, acc[mt][nt], 0, 0, 0);
            }
        }
    }
#pragma unroll
    for (int mt = 0; mt < 2; ++mt) {
#pragma unroll
        for (int r = 0; r < 4; ++r) {
            int row = row_base + mt * 16 + g * 4 + r;
            if (row < n) {
#pragma unroll
                for (int nt = 0; nt < NT; ++nt)
                    C[(size_t)row * OUT_DIM + nt * 16 + rr] = f32_bf16_rn(acc[mt][nt][r]);
            }
        }
    }
}

static inline size_t align_up(size_t x, size_t a) { return (x + a - 1) & ~(a - 1); }

extern "C" void kernel_launch(void* const* d_in, const int* in_sizes, int n_in,
                              void* d_out, int out_size, void* d_ws, size_t ws_size,
                              hipStream_t stream) {
    const float* x  = (const float*)d_in[0];
    const void*  ei = d_in[1];
    const float* ew = (const float*)d_in[2];
    const float* W1 = (const float*)d_in[3];
    const float* b1 = (const float*)d_in[4];
    const float* W2 = (const float*)d_in[5];
    const float* b2 = (const float*)d_in[6];
    float* out = (float*)d_out;

    const int N = N_NODES, E = N_EDGES;

    char* p = (char*)d_ws;
    int*    rows   = (int*)p;    p += align_up((size_t)E * 4, 512);
    int*    cols   = (int*)p;    p += align_up((size_t)E * 4, 512);
    int*    rank   = (int*)p;    p += align_up((size_t)E * 4, 512);
    unsigned int* degcnt = (unsigned int*)p; p += align_up((size_t)N * 4, 512);
    float*  dinv   = (float*)p;  p += align_up((size_t)N * 4, 512);
    int*    starts = (int*)p;    p += align_up((size_t)(N + 1) * 4, 512);
    int*    bsums  = (int*)p;    p += align_up((size_t)256 * 4, 512);
    int2*   packed = (int2*)p;   p += align_up((size_t)E * 8, 512);
    ushort* htmp1  = (ushort*)p; p += align_up((size_t)N * HID_DIM * 2, 512);
    ushort* h1     = (ushort*)p; p += align_up((size_t)N * HID_DIM * 2, 512);
    ushort* htmp2  = (ushort*)p; p += align_up((size_t)N * OUT_DIM * 2, 512);
    ushort* w1hi   = (ushort*)p; p += align_up((size_t)128 * HID_DIM * 2, 512);
    ushort* w1lo   = (ushort*)p; p += align_up((size_t)128 * HID_DIM * 2, 512);
    ushort* w2hi   = (ushort*)p; p += align_up((size_t)128 * OUT_DIM * 2, 512);
    ushort* w2lo   = (ushort*)p; p += align_up((size_t)128 * OUT_DIM * 2, 512);
    (void)ws_size;

    const int B = 256;
    int gE = (E + B - 1) / B;
    int gather_blocks = (int)(((size_t)((N + 1) / 2) * 64 + B - 1) / B);  // 2 nodes/wave

    // ---- prep: zero degcnt + split both W (one tiny launch) ----
    k_prep<<<SCAN_BLOCKS, B, 0, stream>>>(degcnt, W1, w1hi, w1lo, W2, w2hi, w2lo);

    // ---- single 32-bit-atomic edge pass (standalone: VGPR-light) ----
    k_edges_rank<<<EDGE_BLOCKS, B, 0, stream>>>(ei, ew, rows, cols, rank, degcnt, E);

    // ---- GEMM1 (standalone, MFMA) ----
    k_gemm1<<<(N + 127) / 128, 256, 0, stream>>>(x, w1hi, w1lo, htmp1, N);

    // ---- scan + CSR fill ----
    k_scan_block<<<SCAN_BLOCKS, 256, 0, stream>>>(degcnt, starts, bsums, dinv, N);
    k_scan_tops<<<1, 256, 0, stream>>>(bsums, SCAN_BLOCKS);
    k_scan_add<<<SCAN_BLOCKS, 256, 0, stream>>>(starts, bsums, N, E);
    k_fill<<<gE, B, 0, stream>>>(rows, cols, rank, ew, dinv, starts, packed, E);

    // ---- layer 1 aggregate (bf16 rows, ReLU'd bf16 out) ----
    k_gather_b<HID_DIM><<<gather_blocks, B, 0, stream>>>(
        htmp1, packed, starts, dinv, b1, h1, N);

    // ---- layer 2 ----
    k_gemm2<<<(N + 63) / 64, 128, 0, stream>>>(h1, w2hi, w2lo, htmp2, N);
    k_gather_b<OUT_DIM><<<gather_blocks, B, 0, stream>>>(
        htmp2, packed, starts, dinv, b2, out, N);
    (void)out_size; (void)n_in; (void)in_sizes;
}

// Round 9
// 139.904 us; speedup vs baseline: 1.0129x; 1.0129x over previous
//
#include <hip/hip_runtime.h>
#include <hip/hip_bf16.h>
#include <cstdint>

#define N_NODES 50000
#define N_EDGES 640000
#define IN_DIM 128
#define HID_DIM 128
#define OUT_DIM 64
#define NREPL 8

constexpr int EDGE_BLOCKS  = (N_EDGES + 255) / 256;                    // 2500
constexpr int SCAN_BLOCKS  = (N_NODES + 255) / 256;                    // 196
constexpr int WSPLIT_ELEMS = 128 * (HID_DIM + OUT_DIM);                // 24576

typedef __attribute__((ext_vector_type(8))) short bf16x8;
typedef __attribute__((ext_vector_type(4))) float f32x4;

static __device__ __forceinline__ ushort f32_bf16_rn(float f) {
    uint32_t u = __float_as_uint(f);
    u += 0x7fffu + ((u >> 16) & 1u);
    return (ushort)(u >> 16);
}
static __device__ __forceinline__ float bf16_f32(ushort h) {
    return __uint_as_float(((uint32_t)h) << 16);
}

static __device__ __forceinline__ int detect_i64(const void* p) {
    // int64 edge_index (values < 2^31) => every odd int32 word is a zero high-word.
    const int* q = (const int*)p;
    int odd_or = 0, even_or = 0;
#pragma unroll
    for (int i = 1; i < 64; i += 2) odd_or |= q[i];
#pragma unroll
    for (int i = 0; i < 64; i += 2) even_or |= q[i];
    return (odd_or == 0 && even_or != 0) ? 1 : 0;
}

// Prep: zero all 8 degcnt replicas AND split/pack both weight matrices.
// frag = (nt*4 + ks)*64 + g*16 + (j&15), elem e; k = ks*32 + g*8 + e, j = nt*16 + (j&15)
__global__ void k_prep(unsigned int* __restrict__ degcnt_r,
                       const float* __restrict__ W1, ushort* __restrict__ w1hi,
                       ushort* __restrict__ w1lo, const float* __restrict__ W2,
                       ushort* __restrict__ w2hi, ushort* __restrict__ w2lo) {
    int t = blockIdx.x * blockDim.x + threadIdx.x;
    if (t < N_NODES) {
#pragma unroll
        for (int r = 0; r < NREPL; ++r) degcnt_r[r * N_NODES + t] = 0u;
    }
    if (t >= WSPLIT_ELEMS) return;
    const float* W;
    ushort *whi, *wlo;
    int dout, tt = t;
    if (tt < 128 * HID_DIM) {
        W = W1; whi = w1hi; wlo = w1lo; dout = HID_DIM;
    } else {
        tt -= 128 * HID_DIM;
        W = W2; whi = w2hi; wlo = w2lo; dout = OUT_DIM;
    }
    int k = tt / dout, j = tt % dout;
    float w = W[tt];
    ushort hi = f32_bf16_rn(w);
    ushort lo = f32_bf16_rn(w - bf16_f32(hi));
    int nt = j >> 4, ks = k >> 5, g = (k >> 3) & 3, e = k & 7;
    int frag = (nt * 4 + ks) * 64 + g * 16 + (j & 15);
    whi[frag * 8 + e] = hi;
    wlo[frag * 8 + e] = lo;
}

// Single 32-bit atomic per edge into replica (lane&7): 8x fewer same-line
// collisions (theory: L2 same-line atomic RMW serialization is the limiter —
// fill's scattered plain loads/stores run ~6x faster per transaction).
//   degcnt_r[r][c] += (1<<25) + round(w * 2^19)
// bits[25:31] = per-replica edge count (< 128), bits[0:24] = weighted degree
// (2^-19 fixed point, node sum < 64 -> no carry). rank word = (r<<26)|rank_in_r.
__global__ void k_edges_rank(const void* __restrict__ ei, const float* __restrict__ w,
                             int* __restrict__ rows, int* __restrict__ cols,
                             int* __restrict__ rank,
                             unsigned int* __restrict__ degcnt_r, int n_edges) {
    __shared__ int is64_s;
    if (threadIdx.x == 0) is64_s = detect_i64(ei);
    __syncthreads();
    int e = blockIdx.x * blockDim.x + threadIdx.x;
    if (e >= n_edges) return;
    int r, c;
    if (is64_s) {
        const long long* q = (const long long*)ei;
        r = (int)q[e];
        c = (int)q[e + n_edges];
    } else {
        const int* q = (const int*)ei;
        r = q[e];
        c = q[e + n_edges];
    }
    rows[e] = r;
    cols[e] = c;
    int repl = threadIdx.x & (NREPL - 1);
    unsigned int wq = (unsigned int)rintf(w[e] * 524288.0f);  // w * 2^19
    unsigned int old = atomicAdd(&degcnt_r[repl * N_NODES + c], (1u << 25) + wq);
    rank[e] = (repl << 26) | (int)(old >> 25);
}

// GEMM1: C_bf16[n,128] = A_f32[n,128] @ W1 via split-bf16 (3 MFMA products).
__global__ __launch_bounds__(256) void k_gemm1(const float* __restrict__ A,
                                               const ushort* __restrict__ whi_u,
                                               const ushort* __restrict__ wlo_u,
                                               ushort* __restrict__ C, int n) {
    constexpr int NT = HID_DIM / 16;  // 8
    const bf16x8* whi = (const bf16x8*)whi_u;
    const bf16x8* wlo = (const bf16x8*)wlo_u;
    int wave = threadIdx.x >> 6, lane = threadIdx.x & 63;
    int g = lane >> 4, rr = lane & 15;
    int row_base = blockIdx.x * 128 + wave * 32;

    f32x4 acc[2][NT];
#pragma unroll
    for (int mt = 0; mt < 2; ++mt)
#pragma unroll
        for (int nt = 0; nt < NT; ++nt) acc[mt][nt] = (f32x4){0.f, 0.f, 0.f, 0.f};

#pragma unroll
    for (int ks = 0; ks < 4; ++ks) {
        bf16x8 ahi[2], alo[2];
#pragma unroll
        for (int mt = 0; mt < 2; ++mt) {
            int row = row_base + mt * 16 + rr;
            float av[8];
            if (row < n) {
                const float* ap = &A[(size_t)row * IN_DIM + ks * 32 + g * 8];
                float4 p0 = *(const float4*)ap;
                float4 p1 = *(const float4*)(ap + 4);
                av[0] = p0.x; av[1] = p0.y; av[2] = p0.z; av[3] = p0.w;
                av[4] = p1.x; av[5] = p1.y; av[6] = p1.z; av[7] = p1.w;
            } else {
#pragma unroll
                for (int e = 0; e < 8; ++e) av[e] = 0.f;
            }
            union { bf16x8 v; ushort u[8]; } H, L;
#pragma unroll
            for (int e = 0; e < 8; ++e) {
                ushort h = f32_bf16_rn(av[e]);
                H.u[e] = h;
                L.u[e] = f32_bf16_rn(av[e] - bf16_f32(h));
            }
            ahi[mt] = H.v;
            alo[mt] = L.v;
        }
#pragma unroll
        for (int nt = 0; nt < NT; ++nt) {
            bf16x8 wh = whi[(nt * 4 + ks) * 64 + lane];
            bf16x8 wl = wlo[(nt * 4 + ks) * 64 + lane];
#pragma unroll
            for (int mt = 0; mt < 2; ++mt) {
                acc[mt][nt] = __builtin_amdgcn_mfma_f32_16x16x32_bf16(ahi[mt], wh, acc[mt][nt], 0, 0, 0);
                acc[mt][nt] = __builtin_amdgcn_mfma_f32_16x16x32_bf16(alo[mt], wh, acc[mt][nt], 0, 0, 0);
                acc[mt][nt] = __builtin_amdgcn_mfma_f32_16x16x32_bf16(ahi[mt], wl, acc[mt][nt], 0, 0, 0);
            }
        }
    }
    // C/D layout (m89-verified): col = lane&15, row = (lane>>4)*4 + reg
#pragma unroll
    for (int mt = 0; mt < 2; ++mt) {
#pragma unroll
        for (int r = 0; r < 4; ++r) {
            int row = row_base + mt * 16 + g * 4 + r;
            if (row < n) {
#pragma unroll
                for (int nt = 0; nt < NT; ++nt)
                    C[(size_t)row * HID_DIM + nt * 16 + rr] = f32_bf16_rn(acc[mt][nt][r]);
            }
        }
    }
}

// Scan: sum 8 replica counts per node -> exclusive scan of totals; also emits
// per-replica base offsets (repl_base) and dinv.
__global__ void k_scan_block(const unsigned int* __restrict__ degcnt_r,
                             int* __restrict__ starts, int* __restrict__ bsums,
                             unsigned int* __restrict__ repl_base,
                             float* __restrict__ dinv, int n) {
    __shared__ int buf[256];
    int i = blockIdx.x * 256 + threadIdx.x;
    int v = 0;
    if (i < n) {
        unsigned int wsum = 0;
        unsigned int run = 0;
#pragma unroll
        for (int r = 0; r < NREPL; ++r) {
            unsigned int dc = degcnt_r[r * N_NODES + i];
            repl_base[r * N_NODES + i] = run;
            run += dc >> 25;
            wsum += dc & 0x1ffffffu;
        }
        v = (int)run;
        float deg = 1.0f + (float)wsum * (1.0f / 524288.0f);
        dinv[i] = rsqrtf(deg);  // deg >= 1 always (self-loop)
    }
    buf[threadIdx.x] = v;
    __syncthreads();
#pragma unroll
    for (int off = 1; off < 256; off <<= 1) {
        int t = (threadIdx.x >= off) ? buf[threadIdx.x - off] : 0;
        __syncthreads();
        buf[threadIdx.x] += t;
        __syncthreads();
    }
    if (i < n) starts[i] = buf[threadIdx.x] - v;
    if (threadIdx.x == 255) bsums[blockIdx.x] = buf[255];
}

__global__ void k_scan_tops(int* __restrict__ bsums, int nb) {
    __shared__ int buf[256];
    int v = (threadIdx.x < nb) ? bsums[threadIdx.x] : 0;
    buf[threadIdx.x] = v;
    __syncthreads();
#pragma unroll
    for (int off = 1; off < 256; off <<= 1) {
        int t = (threadIdx.x >= off) ? buf[threadIdx.x - off] : 0;
        __syncthreads();
        buf[threadIdx.x] += t;
        __syncthreads();
    }
    if (threadIdx.x < nb) bsums[threadIdx.x] = buf[threadIdx.x] - v;
}

__global__ void k_scan_add(int* __restrict__ starts, const int* __restrict__ bsums,
                           int n, int total) {
    int i = blockIdx.x * 256 + threadIdx.x;
    if (i < n) starts[i] += bsums[blockIdx.x];
    if (i == 0) starts[n] = total;
}

// Atomic-free CSR fill: pos = starts[c] + repl_base[r][c] + rank_in_r.
__global__ void k_fill(const int* __restrict__ rows, const int* __restrict__ cols,
                       const int* __restrict__ rank, const float* __restrict__ w,
                       const float* __restrict__ dinv, const int* __restrict__ starts,
                       const unsigned int* __restrict__ repl_base,
                       int2* __restrict__ packed, int n_edges) {
    int e = blockIdx.x * blockDim.x + threadIdx.x;
    if (e >= n_edges) return;
    int r = rows[e], c = cols[e];
    int rk = rank[e];
    int repl = (rk >> 26) & (NREPL - 1);
    float nm = dinv[r] * w[e] * dinv[c];
    int pos = starts[c] + (int)repl_base[repl * N_NODES + c] + (rk & 0x3ffffff);
    packed[pos] = make_int2(r, __float_as_int(nm));
}

// Gather over bf16 feature rows, one wave per node, unroll-8 (round-7 config:
// readfirstlane'd uniform bounds -> scalar packed loads).
// D=128: lane covers 2 cols (uint = 2 bf16), ReLU'd bf16 output (h1).
// D=64:  lane covers 1 col (ushort), f32 output (final).
template <int D>
__global__ void k_gather_b(const ushort* __restrict__ htmp, const int2* __restrict__ packed,
                           const int* __restrict__ starts, const float* __restrict__ dinv,
                           const float* __restrict__ bias, void* __restrict__ outv, int n) {
    int node = (int)((blockIdx.x * (size_t)blockDim.x + threadIdx.x) >> 6);
    if (node >= n) return;
    int lane = threadIdx.x & 63;
    int beg = __builtin_amdgcn_readfirstlane(starts[node]);
    int end = __builtin_amdgcn_readfirstlane(starts[node + 1]);
    float di = dinv[node];
    float s = di * di;

    if constexpr (D == 128) {
        uint us = ((const uint*)(htmp + (size_t)node * 128))[lane];
        float ax = bf16_f32((ushort)us) * s + bias[lane * 2];
        float ay = bf16_f32((ushort)(us >> 16)) * s + bias[lane * 2 + 1];
        for (int p0 = beg; p0 < end; p0 += 8) {
            int2 e[8];
#pragma unroll
            for (int u = 0; u < 8; ++u) {
                int p = p0 + u;
                e[u] = packed[p < end ? p : end - 1];
            }
            uint v[8];
#pragma unroll
            for (int u = 0; u < 8; ++u)
                v[u] = ((const uint*)(htmp + (size_t)e[u].x * 128))[lane];
#pragma unroll
            for (int u = 0; u < 8; ++u) {
                float nm = (p0 + u < end) ? __int_as_float(e[u].y) : 0.f;
                ax = fmaf(bf16_f32((ushort)v[u]), nm, ax);
                ay = fmaf(bf16_f32((ushort)(v[u] >> 16)), nm, ay);
            }
        }
        // ReLU + pack bf16 pair (h1 feeds layer-2 GEMM directly as exact bf16)
        uint po = (uint)f32_bf16_rn(fmaxf(ax, 0.f)) | ((uint)f32_bf16_rn(fmaxf(ay, 0.f)) << 16);
        ((uint*)((ushort*)outv + (size_t)node * 128))[lane] = po;
    } else {
        float acc = bf16_f32(htmp[(size_t)node * 64 + lane]) * s + bias[lane];
        for (int p0 = beg; p0 < end; p0 += 8) {
            int2 e[8];
#pragma unroll
            for (int u = 0; u < 8; ++u) {
                int p = p0 + u;
                e[u] = packed[p < end ? p : end - 1];
            }
            float v[8];
#pragma unroll
            for (int u = 0; u < 8; ++u)
                v[u] = bf16_f32(htmp[(size_t)e[u].x * 64 + lane]);
#pragma unroll
            for (int u = 0; u < 8; ++u) {
                float nm = (p0 + u < end) ? __int_as_float(e[u].y) : 0.f;
                acc = fmaf(v[u], nm, acc);
            }
        }
        ((float*)outv)[(size_t)node * 64 + lane] = acc;
    }
}

// GEMM2: C_bf16[n,64] = A_bf16[n,128] @ W2, A exact bf16 -> 2 MFMA products.
__global__ __launch_bounds__(128) void k_gemm2(const ushort* __restrict__ A,
                                               const ushort* __restrict__ whi_u,
                                               const ushort* __restrict__ wlo_u,
                                               ushort* __restrict__ C, int n) {
    constexpr int NT = OUT_DIM / 16;  // 4
    const bf16x8* whi = (const bf16x8*)whi_u;
    const bf16x8* wlo = (const bf16x8*)wlo_u;
    int wave = threadIdx.x >> 6, lane = threadIdx.x & 63;
    int g = lane >> 4, rr = lane & 15;
    int row_base = blockIdx.x * 64 + wave * 32;

    f32x4 acc[2][NT];
#pragma unroll
    for (int mt = 0; mt < 2; ++mt)
#pragma unroll
        for (int nt = 0; nt < NT; ++nt) acc[mt][nt] = (f32x4){0.f, 0.f, 0.f, 0.f};

#pragma unroll
    for (int ks = 0; ks < 4; ++ks) {
        bf16x8 a[2];
#pragma unroll
        for (int mt = 0; mt < 2; ++mt) {
            int row = row_base + mt * 16 + rr;
            if (row < n)
                a[mt] = *(const bf16x8*)&A[(size_t)row * HID_DIM + ks * 32 + g * 8];
            else
                a[mt] = (bf16x8){0, 0, 0, 0, 0, 0, 0, 0};
        }
#pragma unroll
        for (int nt = 0; nt < NT; ++nt) {
            bf16x8 wh = whi[(nt * 4 + ks) * 64 + lane];
            bf16x8 wl = wlo[(nt * 4 + ks) * 64 + lane];
#pragma unroll
            for (int mt = 0; mt < 2; ++mt) {
                acc[mt][nt] = __builtin_amdgcn_mfma_f32_16x16x32_bf16(a[mt], wh, acc[mt][nt], 0, 0, 0);
                acc[mt][nt] = __builtin_amdgcn_mfma_f32_16x16x32_bf16(a[mt], wl, acc[mt][nt], 0, 0, 0);
            }
        }
    }
#pragma unroll
    for (int mt = 0; mt < 2; ++mt) {
#pragma unroll
        for (int r = 0; r < 4; ++r) {
            int row = row_base + mt * 16 + g * 4 + r;
            if (row < n) {
#pragma unroll
                for (int nt = 0; nt < NT; ++nt)
                    C[(size_t)row * OUT_DIM + nt * 16 + rr] = f32_bf16_rn(acc[mt][nt][r]);
            }
        }
    }
}

static inline size_t align_up(size_t x, size_t a) { return (x + a - 1) & ~(a - 1); }

extern "C" void kernel_launch(void* const* d_in, const int* in_sizes, int n_in,
                              void* d_out, int out_size, void* d_ws, size_t ws_size,
                              hipStream_t stream) {
    const float* x  = (const float*)d_in[0];
    const void*  ei = d_in[1];
    const float* ew = (const float*)d_in[2];
    const float* W1 = (const float*)d_in[3];
    const float* b1 = (const float*)d_in[4];
    const float* W2 = (const float*)d_in[5];
    const float* b2 = (const float*)d_in[6];
    float* out = (float*)d_out;

    const int N = N_NODES, E = N_EDGES;

    char* p = (char*)d_ws;
    int*    rows   = (int*)p;    p += align_up((size_t)E * 4, 512);
    int*    cols   = (int*)p;    p += align_up((size_t)E * 4, 512);
    int*    rank   = (int*)p;    p += align_up((size_t)E * 4, 512);
    unsigned int* degcnt_r = (unsigned int*)p; p += align_up((size_t)NREPL * N * 4, 512);
    unsigned int* repl_base = (unsigned int*)p; p += align_up((size_t)NREPL * N * 4, 512);
    float*  dinv   = (float*)p;  p += align_up((size_t)N * 4, 512);
    int*    starts = (int*)p;    p += align_up((size_t)(N + 1) * 4, 512);
    int*    bsums  = (int*)p;    p += align_up((size_t)256 * 4, 512);
    int2*   packed = (int2*)p;   p += align_up((size_t)E * 8, 512);
    ushort* htmp1  = (ushort*)p; p += align_up((size_t)N * HID_DIM * 2, 512);
    ushort* h1     = (ushort*)p; p += align_up((size_t)N * HID_DIM * 2, 512);
    ushort* htmp2  = (ushort*)p; p += align_up((size_t)N * OUT_DIM * 2, 512);
    ushort* w1hi   = (ushort*)p; p += align_up((size_t)128 * HID_DIM * 2, 512);
    ushort* w1lo   = (ushort*)p; p += align_up((size_t)128 * HID_DIM * 2, 512);
    ushort* w2hi   = (ushort*)p; p += align_up((size_t)128 * OUT_DIM * 2, 512);
    ushort* w2lo   = (ushort*)p; p += align_up((size_t)128 * OUT_DIM * 2, 512);
    (void)ws_size;

    const int B = 256;
    int gE = (E + B - 1) / B;

    // ---- prep: zero degcnt replicas + split both W ----
    k_prep<<<SCAN_BLOCKS, B, 0, stream>>>(degcnt_r, W1, w1hi, w1lo, W2, w2hi, w2lo);

    // ---- single 32-bit-atomic edge pass, 8-replica (collision-spread) ----
    k_edges_rank<<<EDGE_BLOCKS, B, 0, stream>>>(ei, ew, rows, cols, rank, degcnt_r, E);

    // ---- GEMM1 (standalone, MFMA) ----
    k_gemm1<<<(N + 127) / 128, 256, 0, stream>>>(x, w1hi, w1lo, htmp1, N);

    // ---- scan + CSR fill ----
    k_scan_block<<<SCAN_BLOCKS, 256, 0, stream>>>(degcnt_r, starts, bsums, repl_base, dinv, N);
    k_scan_tops<<<1, 256, 0, stream>>>(bsums, SCAN_BLOCKS);
    k_scan_add<<<SCAN_BLOCKS, 256, 0, stream>>>(starts, bsums, N, E);
    k_fill<<<gE, B, 0, stream>>>(rows, cols, rank, ew, dinv, starts, repl_base, packed, E);

    // ---- layer 1 aggregate (bf16 rows, ReLU'd bf16 out) ----
    k_gather_b<HID_DIM><<<((size_t)N * 64 + B - 1) / B, B, 0, stream>>>(
        htmp1, packed, starts, dinv, b1, h1, N);

    // ---- layer 2 ----
    k_gemm2<<<(N + 63) / 64, 128, 0, stream>>>(h1, w2hi, w2lo, htmp2, N);
    k_gather_b<OUT_DIM><<<((size_t)N * 64 + B - 1) / B, B, 0, stream>>>(
        htmp2, packed, starts, dinv, b2, out, N);
    (void)out_size; (void)n_in; (void)in_sizes;
}